// Round 16
// baseline (304.268 us; speedup 1.0000x reference)
//
#include <hip/hip_runtime.h>

// MPO/TT embedding: out[t] = A2[h(t)] (16x64) . B3[l(t)] (64x48), MFMA edition.
// cores: c0 (1,8,4,32) c1 (32,8,4,64) c2 (64,8,4,64) c3 (64,8,4,24) c4 (24,8,3,1)
// v = token id; h = v>>9 (i1=h>>3,i2=h&7); l = v&511 (i3=l>>6, l2=l&63, i4=l2>>3, i5=l2&7)
// o = o12*48 + o345 ; o12 = o1*4+o2 (16, =M) ; o345 = o3*12+o4*3+o5 (48, =N); r2 = K (64)
//
// R16: R14 dataflow (best, 24.9us), fused into ONE launch. Blocks 0..2111 do
// prep (R14 body verbatim), release-fence, atomicAdd a done-counter in d_ws.
// Blocks 2112+ spin on the counter (t0 only, agent-scope loads + s_sleep),
// acquire-fence, then run the R14 main body (4 tokens/block, 6 MFMA/wave).
// Counter is zeroed per call via 4B hipMemsetAsync (capture-safe, stateless).
// Deadlock-free by capacity: 1024 spinning main blocks = 4096 waves < 8192.
//
// Fragment layouts (R13/R14-validated on HW):
//   A-frag: lane = lh*16+m holds k = ks*32+lh*8+j, j=0..7
//   B-frag: lane = lh*16+n, same k packing
//   A2Tb[h][ks][lane][j] : 128 KB ; B3pb[l][nt][ks][lane][j] : 3 MB
//   C/D: col(n) = lane&15, row(m) = (lane>>4)*4+reg

typedef __attribute__((ext_vector_type(8))) short bf16x8;
typedef __attribute__((ext_vector_type(8))) unsigned short u16x8;
typedef __attribute__((ext_vector_type(4))) float f32x4;

#define N_PREP 2112

__device__ __forceinline__ unsigned short f2bf(float x) {
    unsigned u = __float_as_uint(x);
    unsigned r = (u + 0x7FFFu + ((u >> 16) & 1u)) >> 16;   // RNE
    return (unsigned short)r;
}

__global__ __launch_bounds__(256) void k_fused(const int* __restrict__ ids,
                                               const float* __restrict__ c0,
                                               const float* __restrict__ c1,
                                               const float* __restrict__ c2,
                                               const float* __restrict__ c3,
                                               const float* __restrict__ c4,
                                               unsigned short* __restrict__ A2Tb,
                                               unsigned short* __restrict__ B3pb,
                                               unsigned int* __restrict__ flag,
                                               float* __restrict__ out,
                                               int n_tokens) {
    const int t = threadIdx.x;
    const int b = blockIdx.x;

    if (b < N_PREP) {
        // ================= PREP (R14 body) =================
        if (b >= 2048) {
            // ---- A2 for h = b-2048, packed as A-fragments ----
            if (t < 128) {
                int h = b - 2048;
                int i1 = h >> 3, i2 = h & 7;
                int m = t & 15, kc = t >> 4;            // kc 0..7 ; r2 = kc*8 + j
                int o1 = m >> 2, o2 = m & 3;
                const float* c0r = c0 + i1 * 128 + o1 * 32;
                const float* c1p = c1 + i2 * 256 + o2 * 64 + kc * 8;
                float s[8] = {};
#pragma unroll
                for (int r1 = 0; r1 < 32; ++r1) {
                    float a = c0r[r1];
                    float4 v0 = *reinterpret_cast<const float4*>(c1p + r1 * 2048);
                    float4 v1 = *reinterpret_cast<const float4*>(c1p + r1 * 2048 + 4);
                    s[0] += a * v0.x; s[1] += a * v0.y; s[2] += a * v0.z; s[3] += a * v0.w;
                    s[4] += a * v1.x; s[5] += a * v1.y; s[6] += a * v1.z; s[7] += a * v1.w;
                }
                int ks = kc >> 2, lh = kc & 3;          // lane = lh*16 + m
                unsigned short* dst = A2Tb + (size_t)(((h * 2 + ks) * 64 + lh * 16 + m)) * 8;
                *reinterpret_cast<ushort4*>(dst) =
                    make_ushort4(f2bf(s[0]), f2bf(s[1]), f2bf(s[2]), f2bf(s[3]));
                *reinterpret_cast<ushort4*>(dst + 4) =
                    make_ushort4(f2bf(s[4]), f2bf(s[5]), f2bf(s[6]), f2bf(s[7]));
            }
            __threadfence();            // release stores device-wide
            __syncthreads();
            if (t == 0) atomicAdd(flag, 1u);
            return;
        }

        // ---- B3 quarter: l = b>>2, r2 in [16p, 16p+16) ----
        const int l = b >> 2, p = b & 3;
        const int i3 = l >> 6, l2 = l & 63;
        const int i4 = l2 >> 3, i5 = l2 & 7;
        const int ks = p >> 1, lh0 = (p & 1) * 2;

        __shared__ float B4s[64 * 12];        // [r3][o45]
        __shared__ unsigned short stg[768];   // [nt][lhrel][n][j]

        {
            int r3 = t >> 2, m = t & 3;  // m = o4
            const float* c3p = c3 + r3 * 768 + i4 * 96 + m * 24;
            const float* c4p = c4 + i5 * 3;
            float a0 = 0.f, a1 = 0.f, a2 = 0.f;
#pragma unroll
            for (int r4q = 0; r4q < 24; r4q += 4) {
                float4 cv = *reinterpret_cast<const float4*>(c3p + r4q);
                float cc[4] = {cv.x, cv.y, cv.z, cv.w};
#pragma unroll
                for (int d = 0; d < 4; ++d) {
                    const float* bb = c4p + (r4q + d) * 24;
                    a0 += cc[d] * bb[0];
                    a1 += cc[d] * bb[1];
                    a2 += cc[d] * bb[2];
                }
            }
            float* o = B4s + r3 * 12 + m * 3;
            o[0] = a0; o[1] = a1; o[2] = a2;
        }
        __syncthreads();

        {
            int r2l = t >> 4;                 // 0..15; r2 = 16p + r2l
            int jj = t & 15;
            int r2 = 16 * p + r2l;
            int lhrel = r2l >> 3, j = r2l & 7;
            int o3 = jj >> 2, g = jj & 3;
            const float* c2p = c2 + r2 * 2048 + i3 * 256 + o3 * 64;  // + r3
            float a0 = 0.f, a1 = 0.f, a2 = 0.f;
#pragma unroll
            for (int r3q = 0; r3q < 64; r3q += 4) {
                float4 cv = *reinterpret_cast<const float4*>(c2p + r3q);
                float cc[4] = {cv.x, cv.y, cv.z, cv.w};
#pragma unroll
                for (int d = 0; d < 4; ++d) {
                    const float* bb = B4s + (r3q + d) * 12 + 3 * g;
                    a0 += cc[d] * bb[0];
                    a1 += cc[d] * bb[1];
                    a2 += cc[d] * bb[2];
                }
            }
            float av[3] = {a0, a1, a2};
#pragma unroll
            for (int c = 0; c < 3; ++c) {
                int o345 = 3 * jj + c;
                int nt = o345 >> 4, n = o345 & 15;
                stg[nt * 256 + lhrel * 128 + n * 8 + j] = f2bf(av[c]);
            }
        }
        __syncthreads();

        if (t < 96) {
            int nt = t >> 5, r = (t & 31) * 8;
            u16x8 val = *reinterpret_cast<const u16x8*>(stg + t * 8);
            size_t dst = (size_t)l * 3072 + (size_t)(nt * 2 + ks) * 512 + lh0 * 128 + r;
            *reinterpret_cast<u16x8*>(B3pb + dst) = val;
        }
        __threadfence();                // release stores device-wide
        __syncthreads();
        if (t == 0) atomicAdd(flag, 1u);
        return;
    }

    // ================= MAIN (R14 body), after prep completes =================
    if (t == 0) {
        while (__hip_atomic_load(flag, __ATOMIC_RELAXED, __HIP_MEMORY_SCOPE_AGENT)
               < (unsigned)N_PREP) {
            __builtin_amdgcn_s_sleep(16);
        }
    }
    __syncthreads();
    __threadfence();                    // acquire: invalidate stale cache lines

    const int wave = t >> 6, lane = t & 63;
    const int token = (b - N_PREP) * 4 + wave;
    if (token >= n_tokens) return;

    const int v = ids[token];
    const int h = v >> 9, l = v & 511;

    const bf16x8* A = reinterpret_cast<const bf16x8*>(A2Tb) + h * 128 + lane;
    const bf16x8* B = reinterpret_cast<const bf16x8*>(B3pb) + l * 384 + lane;

    bf16x8 a0 = A[0];
    bf16x8 a1 = A[64];
    f32x4 z = {0.f, 0.f, 0.f, 0.f};

    f32x4 acc0 = __builtin_amdgcn_mfma_f32_16x16x32_bf16(a0, B[0],   z, 0, 0, 0);
    acc0       = __builtin_amdgcn_mfma_f32_16x16x32_bf16(a1, B[64],  acc0, 0, 0, 0);
    f32x4 acc1 = __builtin_amdgcn_mfma_f32_16x16x32_bf16(a0, B[128], z, 0, 0, 0);
    acc1       = __builtin_amdgcn_mfma_f32_16x16x32_bf16(a1, B[192], acc1, 0, 0, 0);
    f32x4 acc2 = __builtin_amdgcn_mfma_f32_16x16x32_bf16(a0, B[256], z, 0, 0, 0);
    acc2       = __builtin_amdgcn_mfma_f32_16x16x32_bf16(a1, B[320], acc2, 0, 0, 0);

    // C/D: col = lane&15 (n within tile), row = (lane>>4)*4 + reg (= o12)
    const int n = lane & 15;
    float* o = out + (size_t)token * 768 + ((lane >> 4) * 4) * 48 + n;
#pragma unroll
    for (int reg = 0; reg < 4; ++reg) {
        o[reg * 48 + 0]  = acc0[reg];
        o[reg * 48 + 16] = acc1[reg];
        o[reg * 48 + 32] = acc2[reg];
    }
}

extern "C" void kernel_launch(void* const* d_in, const int* in_sizes, int n_in,
                              void* d_out, int out_size, void* d_ws, size_t ws_size,
                              hipStream_t stream) {
    const int*   ids = (const int*)d_in[0];
    const float* c0  = (const float*)d_in[1];
    const float* c1  = (const float*)d_in[2];
    const float* c2  = (const float*)d_in[3];
    const float* c3  = (const float*)d_in[4];
    const float* c4  = (const float*)d_in[5];
    float* out = (float*)d_out;

    char* ws = (char*)d_ws;
    unsigned short* A2Tb = (unsigned short*)(ws + 0);        // 131072 B
    unsigned short* B3pb = (unsigned short*)(ws + 131072);   // 3145728 B
    unsigned int*   flag = (unsigned int*)(ws + 3276800);    // 4 B

    int n_tokens = in_sizes[0];             // 8*512 = 4096
    int nb_main = (n_tokens + 3) / 4;       // 1024

    hipMemsetAsync(flag, 0, sizeof(unsigned int), stream);   // capture-safe
    k_fused<<<N_PREP + nb_main, 256, 0, stream>>>(ids, c0, c1, c2, c3, c4,
                                                  A2Tb, B3pb, flag, out, n_tokens);
}

// Round 17
// 23.342 us; speedup vs baseline: 13.0351x; 13.0351x over previous
//
#include <hip/hip_runtime.h>

// MPO/TT embedding: out[t] = A2[h(t)] (16x64) . B3[l(t)] (64x48), MFMA edition.
// cores: c0 (1,8,4,32) c1 (32,8,4,64) c2 (64,8,4,64) c3 (64,8,4,24) c4 (24,8,3,1)
// v = token id; h = v>>9 (i1=h>>3,i2=h&7); l = v&511 (i3=l>>6, l2=l&63, i4=l2>>3, i5=l2&7)
// o = o12*48 + o345 ; o12 (16,=M) ; o345 = o3*12+o4*3+o5 (48) ; r2 = K (64)
//
// R17: prep's B3 contraction moved to MFMA. Per (i3,i4,mh) block:
//   GEMM C[m=(r2,o3)][n=(i5,o45)] = sum_r3 c2[r2,i3,o3,r3] * B4T[r3][i5,o45]
//   A = c2 rows (natural order) -> bf16 A-frags in LDS (coalesced, read-once)
//   B = B4T slice (fixed i4)    -> bf16 B-frags in LDS (computed in-block)
//   C scattered (bf16) into the R13/R14-validated B3pb fragment layout.
// A2-fragment blocks and k_main are R14-verbatim.
//
// Fragment layouts (R13/R14-validated on HW):
//   A-frag: lane = lh*16+m holds k = ks*32+lh*8+j, j=0..7
//   B-frag: lane = lh*16+n, same k packing
//   A2Tb[h][ks][lane][j] : 128 KB ; B3pb[l][nt][ks][lane][j] : 3 MB
//   C/D: col(n) = lane&15, row(m) = (lane>>4)*4+reg

typedef __attribute__((ext_vector_type(8))) short bf16x8;
typedef __attribute__((ext_vector_type(8))) unsigned short u16x8;
typedef __attribute__((ext_vector_type(4))) float f32x4;

__device__ __forceinline__ unsigned short f2bf(float x) {
    unsigned u = __float_as_uint(x);
    unsigned r = (u + 0x7FFFu + ((u >> 16) & 1u)) >> 16;   // RNE
    return (unsigned short)r;
}

// prep grid: blocks 0..127 = B3 GEMM (i3 = b>>4, i4 = (b>>1)&7, mh = b&1)
//            blocks 128..191 = A2 fragments (h = b-128)
__global__ __launch_bounds__(256) void k_prep(const float* __restrict__ c0,
                                              const float* __restrict__ c1,
                                              const float* __restrict__ c2,
                                              const float* __restrict__ c3,
                                              const float* __restrict__ c4,
                                              unsigned short* __restrict__ A2Tb,
                                              unsigned short* __restrict__ B3pb) {
    const int t = threadIdx.x;
    const int b = blockIdx.x;

    if (b >= 128) {
        // ---- A2 for h = b-128, packed as A-fragments (R14 verbatim) ----
        if (t >= 128) return;
        int h = b - 128;
        int i1 = h >> 3, i2 = h & 7;
        int m = t & 15, kc = t >> 4;            // kc 0..7 ; r2 = kc*8 + j
        int o1 = m >> 2, o2 = m & 3;
        const float* c0r = c0 + i1 * 128 + o1 * 32;
        const float* c1p = c1 + i2 * 256 + o2 * 64 + kc * 8;
        float s[8] = {};
#pragma unroll
        for (int r1 = 0; r1 < 32; ++r1) {
            float a = c0r[r1];
            float4 v0 = *reinterpret_cast<const float4*>(c1p + r1 * 2048);
            float4 v1 = *reinterpret_cast<const float4*>(c1p + r1 * 2048 + 4);
            s[0] += a * v0.x; s[1] += a * v0.y; s[2] += a * v0.z; s[3] += a * v0.w;
            s[4] += a * v1.x; s[5] += a * v1.y; s[6] += a * v1.z; s[7] += a * v1.w;
        }
        int ks = kc >> 2, lh = kc & 3;          // lane = lh*16 + m
        unsigned short* dst = A2Tb + (size_t)(((h * 2 + ks) * 64 + lh * 16 + m)) * 8;
        *reinterpret_cast<ushort4*>(dst) =
            make_ushort4(f2bf(s[0]), f2bf(s[1]), f2bf(s[2]), f2bf(s[3]));
        *reinterpret_cast<ushort4*>(dst + 4) =
            make_ushort4(f2bf(s[4]), f2bf(s[5]), f2bf(s[6]), f2bf(s[7]));
        return;
    }

    // ================= B3 GEMM block =================
    const int i3 = b >> 4, i4 = (b >> 1) & 7, mh = b & 1;

    __shared__ unsigned short aFrag[8 * 2 * 64 * 8];   // 16 KB: [mtl][ks][lane][j]
    __shared__ unsigned short bFrag[6 * 2 * 64 * 8];   // 12 KB: [nt][ks][lane][j]

    // ---- stage A: 128 c2 rows (m_global = mh*128 + m_local) -> bf16 frags ----
    {
        int m_local = t >> 1, half = t & 1;            // 2 threads per row
        int m_global = mh * 128 + m_local;
        int r2 = m_global >> 2, o3 = m_global & 3;
        int mtl = m_local >> 4, mm = m_local & 15;
        const float* row = c2 + r2 * 2048 + i3 * 256 + o3 * 64 + half * 32;
#pragma unroll
        for (int cc8 = 0; cc8 < 4; ++cc8) {
            int c8 = half * 4 + cc8;                   // k-chunk: k = c8*8 + j
            float4 v0 = *reinterpret_cast<const float4*>(row + cc8 * 8);
            float4 v1 = *reinterpret_cast<const float4*>(row + cc8 * 8 + 4);
            int ks = c8 >> 2, lh = c8 & 3;
            unsigned short* dst = aFrag + (size_t)(((mtl * 2 + ks) * 64) + lh * 16 + mm) * 8;
            *reinterpret_cast<ushort4*>(dst) =
                make_ushort4(f2bf(v0.x), f2bf(v0.y), f2bf(v0.z), f2bf(v0.w));
            *reinterpret_cast<ushort4*>(dst + 4) =
                make_ushort4(f2bf(v1.x), f2bf(v1.y), f2bf(v1.z), f2bf(v1.w));
        }
    }

    // ---- compute B4T slice (fixed i4) -> bFrag ----
    // thread (r3 = t>>2, o4 = t&3): B4T[r3][n = i5*12 + o4*3 + o5] for i5=0..7,o5=0..2
    {
        int r3 = t >> 2, o4 = t & 3;
        const float* c3p = c3 + r3 * 768 + i4 * 96 + o4 * 24;   // 24 floats
        float cc[24];
#pragma unroll
        for (int q = 0; q < 6; ++q) {
            float4 v = *reinterpret_cast<const float4*>(c3p + q * 4);
            cc[q * 4 + 0] = v.x; cc[q * 4 + 1] = v.y; cc[q * 4 + 2] = v.z; cc[q * 4 + 3] = v.w;
        }
        float acc[8][3] = {};
#pragma unroll
        for (int r4 = 0; r4 < 24; ++r4) {
            float a = cc[r4];
            const float* c4r = c4 + r4 * 24;          // [i5][o5], 24 floats
#pragma unroll
            for (int i5 = 0; i5 < 8; ++i5) {
                acc[i5][0] += a * c4r[i5 * 3 + 0];
                acc[i5][1] += a * c4r[i5 * 3 + 1];
                acc[i5][2] += a * c4r[i5 * 3 + 2];
            }
        }
        int ks = r3 >> 5, lh = (r3 >> 3) & 3, j = r3 & 7;
#pragma unroll
        for (int i5 = 0; i5 < 8; ++i5) {
#pragma unroll
            for (int o5 = 0; o5 < 3; ++o5) {
                int n = i5 * 12 + o4 * 3 + o5;        // 0..95
                int nt = n >> 4, nn = n & 15;
                bFrag[(size_t)(((nt * 2 + ks) * 64) + lh * 16 + nn) * 8 + j] =
                    f2bf(acc[i5][o5]);
            }
        }
    }
    __syncthreads();

    // ---- GEMM + scatter: wave w handles mtl in {2w, 2w+1} ----
    {
        int w = t >> 6, lane = t & 63;
        const bf16x8* A = reinterpret_cast<const bf16x8*>(aFrag);
        const bf16x8* B = reinterpret_cast<const bf16x8*>(bFrag);
        f32x4 z = {0.f, 0.f, 0.f, 0.f};
        const int row4 = (lane >> 4) * 4;             // C row base (m within tile)
        const int ncol = lane & 15;

#pragma unroll
        for (int mi = 0; mi < 2; ++mi) {
            int mtl = w * 2 + mi;
            bf16x8 a0 = A[(mtl * 2 + 0) * 64 + lane];
            bf16x8 a1 = A[(mtl * 2 + 1) * 64 + lane];
#pragma unroll
            for (int nt = 0; nt < 6; ++nt) {
                bf16x8 b0 = B[(nt * 2 + 0) * 64 + lane];
                bf16x8 b1 = B[(nt * 2 + 1) * 64 + lane];
                f32x4 acc = __builtin_amdgcn_mfma_f32_16x16x32_bf16(a0, b0, z, 0, 0, 0);
                acc       = __builtin_amdgcn_mfma_f32_16x16x32_bf16(a1, b1, acc, 0, 0, 0);

                int n = nt * 16 + ncol;               // 0..95
                int l2rel = (n * 171) >> 11;          // n / 12 (exact for n<96)
                int o45 = n - l2rel * 12;
                int l = i3 * 64 + i4 * 8 + l2rel;
                unsigned short* lp = B3pb + (size_t)l * 3072;
                int m_base = mh * 128 + mtl * 16 + row4;   // m_global for reg=0
#pragma unroll
                for (int reg = 0; reg < 4; ++reg) {
                    int m = m_base + reg;
                    int r2 = m >> 2, o3 = m & 3;
                    int o345 = o3 * 12 + o45;
                    int nt2 = o345 >> 4, n2 = o345 & 15;
                    int ks2 = r2 >> 5, lh2 = (r2 >> 3) & 3, j2 = r2 & 7;
                    lp[(size_t)(((nt2 * 2 + ks2) * 64) + lh2 * 16 + n2) * 8 + j2] =
                        f2bf(acc[reg]);
                }
            }
        }
    }
}

// ---- main: one wave per token, 6 MFMA (R13/R14 verbatim) ----
__global__ __launch_bounds__(256) void k_main(const int* __restrict__ ids,
                                              const unsigned short* __restrict__ A2Tb,
                                              const unsigned short* __restrict__ B3pb,
                                              float* __restrict__ out,
                                              int n_tokens) {
    const int t = threadIdx.x;
    const int wave = t >> 6, lane = t & 63;
    const int token = blockIdx.x * 4 + wave;
    if (token >= n_tokens) return;

    const int v = ids[token];
    const int h = v >> 9, l = v & 511;

    const bf16x8* A = reinterpret_cast<const bf16x8*>(A2Tb) + h * 128 + lane;
    const bf16x8* B = reinterpret_cast<const bf16x8*>(B3pb) + l * 384 + lane;

    bf16x8 a0 = A[0];
    bf16x8 a1 = A[64];
    f32x4 z = {0.f, 0.f, 0.f, 0.f};

    f32x4 acc0 = __builtin_amdgcn_mfma_f32_16x16x32_bf16(a0, B[0],   z, 0, 0, 0);
    acc0       = __builtin_amdgcn_mfma_f32_16x16x32_bf16(a1, B[64],  acc0, 0, 0, 0);
    f32x4 acc1 = __builtin_amdgcn_mfma_f32_16x16x32_bf16(a0, B[128], z, 0, 0, 0);
    acc1       = __builtin_amdgcn_mfma_f32_16x16x32_bf16(a1, B[192], acc1, 0, 0, 0);
    f32x4 acc2 = __builtin_amdgcn_mfma_f32_16x16x32_bf16(a0, B[256], z, 0, 0, 0);
    acc2       = __builtin_amdgcn_mfma_f32_16x16x32_bf16(a1, B[320], acc2, 0, 0, 0);

    // C/D: col = lane&15 (n within tile), row = (lane>>4)*4 + reg (= o12)
    const int n = lane & 15;
    float* o = out + (size_t)token * 768 + ((lane >> 4) * 4) * 48 + n;
#pragma unroll
    for (int reg = 0; reg < 4; ++reg) {
        o[reg * 48 + 0]  = acc0[reg];
        o[reg * 48 + 16] = acc1[reg];
        o[reg * 48 + 32] = acc2[reg];
    }
}

extern "C" void kernel_launch(void* const* d_in, const int* in_sizes, int n_in,
                              void* d_out, int out_size, void* d_ws, size_t ws_size,
                              hipStream_t stream) {
    const int*   ids = (const int*)d_in[0];
    const float* c0  = (const float*)d_in[1];
    const float* c1  = (const float*)d_in[2];
    const float* c2  = (const float*)d_in[3];
    const float* c3  = (const float*)d_in[4];
    const float* c4  = (const float*)d_in[5];
    float* out = (float*)d_out;

    char* ws = (char*)d_ws;
    unsigned short* A2Tb = (unsigned short*)(ws + 0);        // 131072 B
    unsigned short* B3pb = (unsigned short*)(ws + 131072);   // 3145728 B (~3.1 MB total)

    int n_tokens = in_sizes[0];             // 8*512 = 4096

    k_prep<<<192, 256, 0, stream>>>(c0, c1, c2, c3, c4, A2Tb, B3pb);
    k_main<<<(n_tokens + 3) / 4, 256, 0, stream>>>(ids, A2Tb, B3pb, out, n_tokens);
}

// Round 18
// 19.975 us; speedup vs baseline: 15.2323x; 1.1686x over previous
//
#include <hip/hip_runtime.h>

// MPO/TT embedding: out[t] = A2[h(t)] (16x64) . B3[l(t)] (64x48)
// cores: c0 (1,8,4,32) c1 (32,8,4,64) c2 (64,8,4,64) c3 (64,8,4,24) c4 (24,8,3,1)
// v = token id; h = v>>9 (i1=h>>3,i2=h&7); l = v&511 (i3=l>>6, l2=l&63, i4=l2>>3, i5=l2&7)
// o = o12*48 + o345 ; o12 (16,=M) ; o345 = o3*12+o4*3+o5 (48) ; r2 = K (64)
//
// R18: B3 never touches global memory. k_mainL = block-per-l (512 blocks):
//   scan ids -> bucket tokens; stage c2 i3-slice as bf16 A-frags (coalesced);
//   compute B4[l2] (72 FMA/thr) as bf16 B-frags; 8 MFMA/wave -> B3[l];
//   scatter C (f32) to LDS as stage-2 B-frags (R17's index math, LDS dest);
//   then each wave independently processes its tokens: 2 A2Tb loads + 6 LDS
//   B-frag reads + 6 MFMA + stores. k_prepA computes only A2Tb (64 blocks).
// Quantization chain identical to R17 -> same absmax expected.
//
// Fragment layouts (R13/R14/R17-validated on HW):
//   A-frag: lane = lh*16+m holds k = ks*32+lh*8+j, j=0..7
//   B-frag: lane = lh*16+n, same k packing
//   A2Tb[h][ks][lane][j] : 128 KB
//   C/D: col(n) = lane&15, row(m) = (lane>>4)*4+reg

typedef __attribute__((ext_vector_type(8))) short bf16x8;
typedef __attribute__((ext_vector_type(4))) float f32x4;

__device__ __forceinline__ unsigned short f2bf(float x) {
    unsigned u = __float_as_uint(x);
    unsigned r = (u + 0x7FFFu + ((u >> 16) & 1u)) >> 16;   // RNE
    return (unsigned short)r;
}

// ---- prep: A2 fragments only (64 blocks, R14/R17 verbatim) ----
__global__ __launch_bounds__(256) void k_prepA(const float* __restrict__ c0,
                                               const float* __restrict__ c1,
                                               unsigned short* __restrict__ A2Tb) {
    const int t = threadIdx.x;
    if (t >= 128) return;
    int h = blockIdx.x;
    int i1 = h >> 3, i2 = h & 7;
    int m = t & 15, kc = t >> 4;            // kc 0..7 ; r2 = kc*8 + j
    int o1 = m >> 2, o2 = m & 3;
    const float* c0r = c0 + i1 * 128 + o1 * 32;
    const float* c1p = c1 + i2 * 256 + o2 * 64 + kc * 8;
    float s[8] = {};
#pragma unroll
    for (int r1 = 0; r1 < 32; ++r1) {
        float a = c0r[r1];
        float4 v0 = *reinterpret_cast<const float4*>(c1p + r1 * 2048);
        float4 v1 = *reinterpret_cast<const float4*>(c1p + r1 * 2048 + 4);
        s[0] += a * v0.x; s[1] += a * v0.y; s[2] += a * v0.z; s[3] += a * v0.w;
        s[4] += a * v1.x; s[5] += a * v1.y; s[6] += a * v1.z; s[7] += a * v1.w;
    }
    int ks = kc >> 2, lh = kc & 3;          // lane = lh*16 + m
    unsigned short* dst = A2Tb + (size_t)(((h * 2 + ks) * 64 + lh * 16 + m)) * 8;
    *reinterpret_cast<ushort4*>(dst) =
        make_ushort4(f2bf(s[0]), f2bf(s[1]), f2bf(s[2]), f2bf(s[3]));
    *reinterpret_cast<ushort4*>(dst + 4) =
        make_ushort4(f2bf(s[4]), f2bf(s[5]), f2bf(s[6]), f2bf(s[7]));
}

// ---- main: block per l; B3 computed in-LDS via MFMA; tokens wave-parallel ----
#define MAX_TOK 128
__global__ __launch_bounds__(256) void k_mainL(const int* __restrict__ ids,
                                               const float* __restrict__ c2,
                                               const float* __restrict__ c3,
                                               const float* __restrict__ c4,
                                               const unsigned short* __restrict__ A2Tb,
                                               float* __restrict__ out,
                                               int n_tokens) {
    const int l = blockIdx.x;
    const int t = threadIdx.x;
    const int i3 = l >> 6, l2 = l & 63;
    const int i4 = l2 >> 3, i5 = l2 & 7;
    const int w = t >> 6, lane = t & 63;

    __shared__ unsigned short aFrag[16 * 2 * 64 * 8];  // 32 KB [mtl][ks][lane][j]
    __shared__ unsigned short bFrag[2 * 64 * 8];       // 2 KB  [ks][lane][j]
    __shared__ unsigned short bFrag2[3 * 2 * 64 * 8];  // 6 KB  [nt][ks][lane][j]
    __shared__ int s_list[MAX_TOK];
    __shared__ int s_cnt;

    // phase 0: init (bFrag fully zeroed: N=12<16 padding must be 0)
    if (t == 0) s_cnt = 0;
    reinterpret_cast<int*>(bFrag)[t] = 0;
    reinterpret_cast<int*>(bFrag)[t + 256] = 0;
    __syncthreads();

    // phase 1a: scan & bucket tokens with l(v)==l
    for (int i = t; i < n_tokens; i += 256) {
        int v = ids[i];
        if ((v & 511) == l) {
            int p = atomicAdd(&s_cnt, 1);
            if (p < MAX_TOK) s_list[p] = (i << 6) | (v >> 9);
        }
    }

    // phase 1b: stage c2 i3-slice -> bf16 A-frags (coalesced: 1KB/instr/wave)
    // wave w, iter it: r2 = w + 4*it ; lane: o3 = lane>>4, chunk = lane&15
    {
        int o3 = lane >> 4, chunk = lane & 15;
        int ks = chunk >> 3, lh = (chunk >> 1) & 3, e4 = (chunk & 1) * 4;
#pragma unroll
        for (int it = 0; it < 16; ++it) {
            int r2 = w + 4 * it;
            float4 v = *reinterpret_cast<const float4*>(
                c2 + r2 * 2048 + i3 * 256 + o3 * 64 + chunk * 4);
            int m = r2 * 4 + o3;
            int mtl = m >> 4, mm = m & 15;
            unsigned short* dst = aFrag +
                (((mtl * 2 + ks) * 64 + lh * 16 + mm) * 8 + e4);
            *reinterpret_cast<ushort4*>(dst) =
                make_ushort4(f2bf(v.x), f2bf(v.y), f2bf(v.z), f2bf(v.w));
        }
    }

    // phase 1c: B4[l2][r3][o45] -> bf16 B-frags (thread: r3 = t>>2, o4 = t&3)
    {
        int r3 = t >> 2, o4 = t & 3;
        const float* c3p = c3 + r3 * 768 + i4 * 96 + o4 * 24;
        float cc[24];
#pragma unroll
        for (int q = 0; q < 6; ++q) {
            float4 v = *reinterpret_cast<const float4*>(c3p + q * 4);
            cc[q * 4 + 0] = v.x; cc[q * 4 + 1] = v.y;
            cc[q * 4 + 2] = v.z; cc[q * 4 + 3] = v.w;
        }
        float s0 = 0.f, s1 = 0.f, s2 = 0.f;
        const float* c4b = c4 + i5 * 3;
#pragma unroll
        for (int r4 = 0; r4 < 24; ++r4) {
            float a = cc[r4];
            const float* bb = c4b + r4 * 24;
            s0 += a * bb[0];
            s1 += a * bb[1];
            s2 += a * bb[2];
        }
        int ks = r3 >> 5, lh = (r3 >> 3) & 3, j = r3 & 7;
        int n0 = o4 * 3;
        bFrag[(ks * 64 + lh * 16 + n0 + 0) * 8 + j] = f2bf(s0);
        bFrag[(ks * 64 + lh * 16 + n0 + 1) * 8 + j] = f2bf(s1);
        bFrag[(ks * 64 + lh * 16 + n0 + 2) * 8 + j] = f2bf(s2);
    }
    __syncthreads();

    const int cnt = (s_cnt < MAX_TOK) ? s_cnt : MAX_TOK;
    if (cnt == 0) return;

    // phase 2: stage-1 GEMM B3 = C2slice . B4  (M=256,N=12,K=64), scatter to LDS
    {
        const bf16x8* A = reinterpret_cast<const bf16x8*>(aFrag);
        const bf16x8* B = reinterpret_cast<const bf16x8*>(bFrag);
        bf16x8 b0 = B[lane];
        bf16x8 b1 = B[64 + lane];
        f32x4 z = {0.f, 0.f, 0.f, 0.f};
        int row4 = (lane >> 4) * 4, ncol = lane & 15;
#pragma unroll
        for (int mi = 0; mi < 4; ++mi) {
            int mtl = w * 4 + mi;
            bf16x8 a0 = A[(mtl * 2 + 0) * 64 + lane];
            bf16x8 a1 = A[(mtl * 2 + 1) * 64 + lane];
            f32x4 acc = __builtin_amdgcn_mfma_f32_16x16x32_bf16(a0, b0, z, 0, 0, 0);
            acc       = __builtin_amdgcn_mfma_f32_16x16x32_bf16(a1, b1, acc, 0, 0, 0);
            if (ncol < 12) {
#pragma unroll
                for (int reg = 0; reg < 4; ++reg) {
                    int m = mtl * 16 + row4 + reg;
                    int r2 = m >> 2, o3 = m & 3;
                    int o345 = o3 * 12 + ncol;
                    int nt2 = o345 >> 4, n2 = o345 & 15;
                    int ks2 = r2 >> 5, lh2 = (r2 >> 3) & 3, j2 = r2 & 7;
                    bFrag2[((nt2 * 2 + ks2) * 64 + lh2 * 16 + n2) * 8 + j2] =
                        f2bf(acc[reg]);
                }
            }
        }
    }
    __syncthreads();

    // phase 3: per-token product (wave-parallel, no syncs)
    {
        const bf16x8* B = reinterpret_cast<const bf16x8*>(bFrag2);
        f32x4 z = {0.f, 0.f, 0.f, 0.f};
        for (int k = w; k < cnt; k += 4) {
            int e = s_list[k];
            int token = e >> 6, h = e & 63;
            const bf16x8* A = reinterpret_cast<const bf16x8*>(A2Tb) + h * 128 + lane;
            bf16x8 a0 = A[0];
            bf16x8 a1 = A[64];

            f32x4 acc0 = __builtin_amdgcn_mfma_f32_16x16x32_bf16(a0, B[lane],       z, 0, 0, 0);
            acc0       = __builtin_amdgcn_mfma_f32_16x16x32_bf16(a1, B[64 + lane],  acc0, 0, 0, 0);
            f32x4 acc1 = __builtin_amdgcn_mfma_f32_16x16x32_bf16(a0, B[128 + lane], z, 0, 0, 0);
            acc1       = __builtin_amdgcn_mfma_f32_16x16x32_bf16(a1, B[192 + lane], acc1, 0, 0, 0);
            f32x4 acc2 = __builtin_amdgcn_mfma_f32_16x16x32_bf16(a0, B[256 + lane], z, 0, 0, 0);
            acc2       = __builtin_amdgcn_mfma_f32_16x16x32_bf16(a1, B[320 + lane], acc2, 0, 0, 0);

            const int n = lane & 15;
            float* o = out + (size_t)token * 768 + ((lane >> 4) * 4) * 48 + n;
#pragma unroll
            for (int reg = 0; reg < 4; ++reg) {
                o[reg * 48 + 0]  = acc0[reg];
                o[reg * 48 + 16] = acc1[reg];
                o[reg * 48 + 32] = acc2[reg];
            }
        }
    }
}

extern "C" void kernel_launch(void* const* d_in, const int* in_sizes, int n_in,
                              void* d_out, int out_size, void* d_ws, size_t ws_size,
                              hipStream_t stream) {
    const int*   ids = (const int*)d_in[0];
    const float* c0  = (const float*)d_in[1];
    const float* c1  = (const float*)d_in[2];
    const float* c2  = (const float*)d_in[3];
    const float* c3  = (const float*)d_in[4];
    const float* c4  = (const float*)d_in[5];
    float* out = (float*)d_out;

    char* ws = (char*)d_ws;
    unsigned short* A2Tb = (unsigned short*)(ws + 0);   // 131072 B

    int n_tokens = in_sizes[0];             // 8*512 = 4096

    k_prepA<<<64, 256, 0, stream>>>(c0, c1, A2Tb);
    k_mainL<<<512, 256, 0, stream>>>(ids, c2, c3, c4, A2Tb, out, n_tokens);
}